// Round 1
// baseline (85.995 us; speedup 1.0000x reference)
//
#include <hip/hip_runtime.h>

#define B_ 64
#define N_ 768
#define F_ 256
#define P_ 64
#define T_ 16
#define K_ 3
#define L_ 12  // N_/P_

// ---------------------------------------------------------------------------
// Kernel 1: pooled_x [B, T*L, F]
// y[b,t,l,f] = conv_b[t] + sum_{p,k} x[b, p*L+l, f+k-1] * w[t,p,k]  (zero-pad f)
// One block per (b,l), 256 threads = one f column each.
// ---------------------------------------------------------------------------
__global__ __launch_bounds__(256) void pool_x_kernel(
    const float* __restrict__ x, const float* __restrict__ conv_w,
    const float* __restrict__ conv_b, float* __restrict__ out)
{
    __shared__ float xt[P_][F_];  // 64 KB
    const int blk = blockIdx.x;
    const int b = blk / L_, l = blk % L_;
    const int f = threadIdx.x;

    const float* xb = x + (size_t)b * N_ * F_ + (size_t)l * F_;
    #pragma unroll 8
    for (int p = 0; p < P_; ++p) {
        xt[p][f] = xb[(size_t)p * (L_ * F_) + f];
    }
    __syncthreads();

    float acc[T_];
    #pragma unroll
    for (int t = 0; t < T_; ++t) acc[t] = conv_b[t];

    for (int p = 0; p < P_; ++p) {
        const float xm = (f > 0)      ? xt[p][f - 1] : 0.f;
        const float x0 = xt[p][f];
        const float xp = (f < F_ - 1) ? xt[p][f + 1] : 0.f;
        const float* wp = conv_w + p * K_;
        #pragma unroll
        for (int t = 0; t < T_; ++t) {
            const float w0 = wp[t * (P_ * K_) + 0];
            const float w1 = wp[t * (P_ * K_) + 1];
            const float w2 = wp[t * (P_ * K_) + 2];
            acc[t] = fmaf(xm, w0, fmaf(x0, w1, fmaf(xp, w2, acc[t])));
        }
    }

    float* ob = out + (size_t)b * (T_ * L_) * F_ + f;
    #pragma unroll
    for (int t = 0; t < T_; ++t) {
        ob[(size_t)(t * L_ + l) * F_] = acc[t];
    }
}

// ---------------------------------------------------------------------------
// Kernel 2: pooled_adj [B, L*T, L*T]
// s[t,p] = sum_k w[t,p,k] * re[k]
// out[b, l*T+t, m*T+u] = sum_{p,q} s[t,p] * adj[b, l*P+p, m*P+q] * s[u,q]
// One block per (b,l), 256 threads.
// ---------------------------------------------------------------------------
#define SSTRIDE 68   // 64+4 pad
#define TSTRIDE 772  // 768+4 pad

__global__ __launch_bounds__(256) void pool_adj_kernel(
    const float* __restrict__ adj, const float* __restrict__ conv_w,
    const float* __restrict__ re_param, float* __restrict__ out)
{
    __shared__ float s_lds[T_][SSTRIDE];   // ~4.3 KB
    __shared__ float tmp[T_][TSTRIDE];     // ~49.4 KB

    const int blk = blockIdx.x;
    const int b = blk / L_, l = blk % L_;
    const int tid = threadIdx.x;

    // s[t][p] = sum_k conv_w[t,p,k] * re_param[k]
    const float r0 = re_param[0], r1 = re_param[1], r2 = re_param[2];
    for (int i = tid; i < T_ * P_; i += 256) {
        const int t = i / P_, p = i % P_;
        const float* w = conv_w + (size_t)i * K_;
        s_lds[t][p] = w[0] * r0 + w[1] * r1 + w[2] * r2;
    }
    __syncthreads();

    // Phase A: tmp[t][c] = sum_p s[t][p] * adj[b, l*P+p, c], 3 cols per thread
    float acc0[T_], acc1[T_], acc2[T_];
    #pragma unroll
    for (int t = 0; t < T_; ++t) { acc0[t] = 0.f; acc1[t] = 0.f; acc2[t] = 0.f; }

    const float* ab = adj + (size_t)b * N_ * N_ + (size_t)(l * P_) * N_;
    for (int p = 0; p < P_; ++p) {
        const float* row = ab + (size_t)p * N_;
        const float a0 = row[tid];
        const float a1 = row[tid + 256];
        const float a2 = row[tid + 512];
        #pragma unroll
        for (int t = 0; t < T_; ++t) {
            const float sv = s_lds[t][p];
            acc0[t] = fmaf(sv, a0, acc0[t]);
            acc1[t] = fmaf(sv, a1, acc1[t]);
            acc2[t] = fmaf(sv, a2, acc2[t]);
        }
    }
    #pragma unroll
    for (int t = 0; t < T_; ++t) {
        tmp[t][tid]       = acc0[t];
        tmp[t][tid + 256] = acc1[t];
        tmp[t][tid + 512] = acc2[t];
    }
    __syncthreads();

    // Phase B: thread = (t,u); out[b, l*T+t, m*T+u] = sum_q tmp[t][m*P+q]*s[u][q]
    const int t = tid >> 4, u = tid & 15;
    float sum[L_];
    #pragma unroll
    for (int m = 0; m < L_; ++m) sum[m] = 0.f;
    for (int q = 0; q < P_; ++q) {
        const float sq = s_lds[u][q];
        #pragma unroll
        for (int m = 0; m < L_; ++m)
            sum[m] = fmaf(tmp[t][m * P_ + q], sq, sum[m]);
    }

    float* ob = out + (size_t)b * (L_ * T_) * (L_ * T_)
                    + (size_t)(l * T_ + t) * (L_ * T_) + u;
    #pragma unroll
    for (int m = 0; m < L_; ++m)
        ob[m * T_] = sum[m];
}

// ---------------------------------------------------------------------------
extern "C" void kernel_launch(void* const* d_in, const int* in_sizes, int n_in,
                              void* d_out, int out_size, void* d_ws, size_t ws_size,
                              hipStream_t stream) {
    (void)in_sizes; (void)n_in; (void)out_size; (void)d_ws; (void)ws_size;
    const float* x        = (const float*)d_in[0];
    const float* adj      = (const float*)d_in[1];
    const float* conv_w   = (const float*)d_in[2];
    const float* conv_b   = (const float*)d_in[3];
    const float* re_param = (const float*)d_in[4];

    float* pooled_x   = (float*)d_out;
    float* pooled_adj = (float*)d_out + (size_t)B_ * (T_ * L_) * F_;

    pool_x_kernel<<<B_ * L_, 256, 0, stream>>>(x, conv_w, conv_b, pooled_x);
    pool_adj_kernel<<<B_ * L_, 256, 0, stream>>>(adj, conv_w, re_param, pooled_adj);
}

// Round 2
// 76.116 us; speedup vs baseline: 1.1298x; 1.1298x over previous
//
#include <hip/hip_runtime.h>

#define B_ 64
#define N_ 768
#define F_ 256
#define P_ 64
#define T_ 16
#define K_ 3
#define L_ 12           // N_/P_
#define TSTRIDE 772     // dwords; row byte-stride 3088: 16B-aligned, ==4 mod 32 banks

// Fused kernel. role = blockIdx&1:
//   role 1: pooled_x  (conv over patches) — no LDS use, L1-served stencil
//   role 0: pooled_adj (s @ A @ s^T per lead-block) — LDS 53.5 KB -> 3 blocks/CU
__global__ __launch_bounds__(256) void fused_pool_kernel(
    const float* __restrict__ x, const float* __restrict__ adj,
    const float* __restrict__ conv_w, const float* __restrict__ conv_b,
    const float* __restrict__ re_param,
    float* __restrict__ out_x, float* __restrict__ out_adj)
{
    __shared__ float sT[P_][T_];         // 4 KB: sT[p][t] = s[t,p]
    __shared__ float tmp[T_][TSTRIDE];   // 49.4 KB

    const int blk  = blockIdx.x;
    const int role = blk & 1;
    const int idx  = blk >> 1;
    const int b = idx / L_, l = idx % L_;
    const int tid = threadIdx.x;

    if (role == 1) {
        // ---------------- pooled_x ----------------
        // y[b,t,l,f] = conv_b[t] + sum_{p,k} x[b, p*L+l, f+k-1] * w[t,p,k]
        const int f = tid;
        const float* xb = x + (size_t)b * N_ * F_ + (size_t)l * F_;

        float acc[T_];
        #pragma unroll
        for (int t = 0; t < T_; ++t) acc[t] = conv_b[t];

        for (int p = 0; p < P_; ++p) {
            const float* row = xb + (size_t)p * (L_ * F_);
            const float xm = (f > 0)      ? row[f - 1] : 0.f;
            const float x0 = row[f];
            const float xp = (f < F_ - 1) ? row[f + 1] : 0.f;
            const float* wp = conv_w + p * K_;   // + t*(P_*K_) + k, thread-uniform
            #pragma unroll
            for (int t = 0; t < T_; ++t) {
                const float w0 = wp[t * (P_ * K_) + 0];
                const float w1 = wp[t * (P_ * K_) + 1];
                const float w2 = wp[t * (P_ * K_) + 2];
                acc[t] = fmaf(xm, w0, fmaf(x0, w1, fmaf(xp, w2, acc[t])));
            }
        }
        float* ob = out_x + (size_t)b * (T_ * L_) * F_ + f;
        #pragma unroll
        for (int t = 0; t < T_; ++t)
            ob[(size_t)(t * L_ + l) * F_] = acc[t];
        return;
    }

    // ---------------- pooled_adj ----------------
    // s[t,p] = sum_k w[t,p,k]*re[k];  out = s @ A_block @ s^T per (l,m) block
    const float r0 = re_param[0], r1 = re_param[1], r2 = re_param[2];
    for (int i = tid; i < P_ * T_; i += 256) {
        const int p = i >> 4, t = i & 15;
        const float* wv = conv_w + (size_t)t * (P_ * K_) + (size_t)p * K_;
        sT[p][t] = wv[0] * r0 + wv[1] * r1 + wv[2] * r2;
    }
    __syncthreads();

    // Phase A: tmp[t][c] = sum_p sT[p][t] * adj[b, l*P+p, c]
    // wave w owns t in [4w,4w+4); lane ct owns cols ct*4 + {0..3} + i*256, i=0..2
    const int w  = tid >> 6;
    const int ct = tid & 63;

    float acc[4][12];
    #pragma unroll
    for (int j = 0; j < 4; ++j)
        #pragma unroll
        for (int c = 0; c < 12; ++c) acc[j][c] = 0.f;

    const float* ab = adj + (size_t)b * N_ * N_ + (size_t)(l * P_) * N_;
    for (int p = 0; p < P_; ++p) {
        const float* row = ab + (size_t)p * N_;
        const float4 a0 = *(const float4*)&row[ct * 4];
        const float4 a1 = *(const float4*)&row[ct * 4 + 256];
        const float4 a2 = *(const float4*)&row[ct * 4 + 512];
        #pragma unroll
        for (int j = 0; j < 4; ++j) {
            const float sv = sT[p][4 * w + j];   // wave-uniform broadcast
            acc[j][0]  = fmaf(sv, a0.x, acc[j][0]);
            acc[j][1]  = fmaf(sv, a0.y, acc[j][1]);
            acc[j][2]  = fmaf(sv, a0.z, acc[j][2]);
            acc[j][3]  = fmaf(sv, a0.w, acc[j][3]);
            acc[j][4]  = fmaf(sv, a1.x, acc[j][4]);
            acc[j][5]  = fmaf(sv, a1.y, acc[j][5]);
            acc[j][6]  = fmaf(sv, a1.z, acc[j][6]);
            acc[j][7]  = fmaf(sv, a1.w, acc[j][7]);
            acc[j][8]  = fmaf(sv, a2.x, acc[j][8]);
            acc[j][9]  = fmaf(sv, a2.y, acc[j][9]);
            acc[j][10] = fmaf(sv, a2.z, acc[j][10]);
            acc[j][11] = fmaf(sv, a2.w, acc[j][11]);
        }
    }
    #pragma unroll
    for (int j = 0; j < 4; ++j) {
        #pragma unroll
        for (int i = 0; i < 3; ++i) {
            float4 v;
            v.x = acc[j][i * 4 + 0]; v.y = acc[j][i * 4 + 1];
            v.z = acc[j][i * 4 + 2]; v.w = acc[j][i * 4 + 3];
            *(float4*)&tmp[4 * w + j][ct * 4 + i * 256] = v;
        }
    }
    __syncthreads();

    // Phase B: out[b, l*T+t, m*T+u] = sum_q tmp[t][m*64+q] * sT[q][u]
    const int t = tid >> 4, u = tid & 15;
    float sum[L_];
    #pragma unroll
    for (int m = 0; m < L_; ++m) sum[m] = 0.f;

    for (int q4 = 0; q4 < P_; q4 += 4) {
        const float s0 = sT[q4 + 0][u];
        const float s1 = sT[q4 + 1][u];
        const float s2 = sT[q4 + 2][u];
        const float s3 = sT[q4 + 3][u];
        #pragma unroll
        for (int m = 0; m < L_; ++m) {
            const float4 tv = *(const float4*)&tmp[t][m * P_ + q4];
            sum[m] = fmaf(tv.x, s0, fmaf(tv.y, s1, fmaf(tv.z, s2, fmaf(tv.w, s3, sum[m]))));
        }
    }

    float* ob = out_adj + (size_t)b * (L_ * T_) * (L_ * T_)
                        + (size_t)(l * T_ + t) * (L_ * T_) + u;
    #pragma unroll
    for (int m = 0; m < L_; ++m)
        ob[m * T_] = sum[m];
}

// ---------------------------------------------------------------------------
extern "C" void kernel_launch(void* const* d_in, const int* in_sizes, int n_in,
                              void* d_out, int out_size, void* d_ws, size_t ws_size,
                              hipStream_t stream) {
    (void)in_sizes; (void)n_in; (void)out_size; (void)d_ws; (void)ws_size;
    const float* x        = (const float*)d_in[0];
    const float* adj      = (const float*)d_in[1];
    const float* conv_w   = (const float*)d_in[2];
    const float* conv_b   = (const float*)d_in[3];
    const float* re_param = (const float*)d_in[4];

    float* pooled_x   = (float*)d_out;
    float* pooled_adj = (float*)d_out + (size_t)B_ * (T_ * L_) * F_;

    fused_pool_kernel<<<B_ * L_ * 2, 256, 0, stream>>>(
        x, adj, conv_w, conv_b, re_param, pooled_x, pooled_adj);
}